// Round 7
// baseline (187.363 us; speedup 1.0000x reference)
//
#include <hip/hip_runtime.h>

typedef unsigned short ushort_t;
typedef __attribute__((ext_vector_type(8))) short bf16x8;
typedef __attribute__((ext_vector_type(4))) short s16x4;
typedef __attribute__((ext_vector_type(4))) float f32x4;

#define BATCH 8
#define SEQ   1024
#define MEMT  8
#define LREAL 1032
#define LPAD  1152   // 9 * 128
#define DMODEL 768
#define NH    12
#define DH    64

// 0.125 * log2(e): Q pre-scaled in GEMM epilogue so attn does exp2(s) directly.
#define CEXP 0.18033688011112042f

__device__ __forceinline__ ushort_t f2b(float x) {
  union { float f; unsigned u; } c; c.f = x;
  unsigned u = c.u;
  unsigned r = (u + 0x7fffu + ((u >> 16) & 1u)) >> 16;
  return (ushort_t)r;
}

#if defined(__has_builtin)
#if __has_builtin(__builtin_amdgcn_global_load_lds)
#define HAVE_GLL 1
#endif
#if __has_builtin(__builtin_amdgcn_exp2f)
#define EXP2F(x) __builtin_amdgcn_exp2f(x)
#endif
#endif
#ifndef EXP2F
#define EXP2F(x) __expf((x) * 0.6931471805599453f)
#endif

// Raw barrier with fine-grained vmcnt (keeps newest DMA prefetches in flight) PLUS
// lgkmcnt(0): all LDS ops must complete before any wave crosses — required because the
// scheduler can sink register-only MFMAs (and their lgkm waits) below the barrier,
// leaving ds_reads in flight when another wave's global_load_lds recycles the buffer.
#define WAITBAR_0 asm volatile("s_waitcnt vmcnt(0) lgkmcnt(0)\n\ts_barrier" ::: "memory")
#define WAITBAR_2 asm volatile("s_waitcnt vmcnt(2) lgkmcnt(0)\n\ts_barrier" ::: "memory")
#define WAITBAR_4 asm volatile("s_waitcnt vmcnt(4) lgkmcnt(0)\n\ts_barrier" ::: "memory")

__device__ __forceinline__ void stage16(const ushort_t* g, ushort_t* lds_wave_base) {
#ifdef HAVE_GLL
  __builtin_amdgcn_global_load_lds(
      (const __attribute__((address_space(1))) unsigned int*)g,
      (__attribute__((address_space(3))) unsigned int*)lds_wave_base,
      16, 0, 0);
#else
  int lane = threadIdx.x & 63;
  *(bf16x8*)(lds_wave_base + lane * 8) = *(const bf16x8*)g;
#endif
}

// Merged prep: blocks [0,6912) build Xm; [6912,8640) cast weights.
__global__ __launch_bounds__(256) void prep(const float* __restrict__ hidden,
                                            const float* __restrict__ memv,
                                            const float* __restrict__ Wq,
                                            const float* __restrict__ Wk,
                                            const float* __restrict__ Wv,
                                            ushort_t* __restrict__ Xm,
                                            ushort_t* __restrict__ Wqb,
                                            ushort_t* __restrict__ Wkb,
                                            ushort_t* __restrict__ Wvb) {
  int bx = blockIdx.x;
  if (bx < 6912) {
    unsigned idx = ((unsigned)bx * 256u + threadIdx.x) * 4u;
    const unsigned perB = (unsigned)LPAD * DMODEL;
    unsigned b = idx / perB;
    unsigned rem = idx - b * perB;
    unsigned row = rem / DMODEL;
    unsigned col = rem - row * DMODEL;
    f32x4 v;
    if (row < SEQ) {
      v = *(const f32x4*)(hidden + ((size_t)b * SEQ + row) * DMODEL + col);
    } else if (row < LREAL) {
      v = *(const f32x4*)(memv + (size_t)(row - SEQ) * DMODEL + col);
    } else {
      v = (f32x4){0.f, 0.f, 0.f, 0.f};
    }
    s16x4 p;
    p[0] = (short)f2b(v[0]); p[1] = (short)f2b(v[1]);
    p[2] = (short)f2b(v[2]); p[3] = (short)f2b(v[3]);
    *(s16x4*)(Xm + idx) = p;
  } else {
    int t = bx - 6912;
    int m = t / 576;
    int i = (t - m * 576) * 256 + threadIdx.x;
    const float* src = m == 0 ? Wq : (m == 1 ? Wk : Wv);
    ushort_t* dst = m == 0 ? Wqb : (m == 1 ? Wkb : Wvb);
    f32x4 v = *(const f32x4*)(src + (size_t)i * 4);
    s16x4 p;
    p[0] = (short)f2b(v[0]); p[1] = (short)f2b(v[1]);
    p[2] = (short)f2b(v[2]); p[3] = (short)f2b(v[3]);
    *(s16x4*)(dst + (size_t)i * 4) = p;
  }
}

// Fused QKV projection: triple-buffered K-loop, raw-barrier vmcnt pipeline (never drains
// the newest prefetch). BK=32, 512 threads, 8 waves 2x4 over 128x128. XCD-pinned grid.
__global__ __launch_bounds__(512, 4) void gemm_fused(
    const ushort_t* __restrict__ Xm,
    const ushort_t* __restrict__ Wqb, const ushort_t* __restrict__ Wkb,
    const ushort_t* __restrict__ Wvb,
    const float* __restrict__ bq, const float* __restrict__ bk,
    const float* __restrict__ bv,
    ushort_t* __restrict__ Qb, ushort_t* __restrict__ Kb,
    ushort_t* __restrict__ Vtb) {
  // 3 bufs @ i*8192: As @ +0 (128x32), Bs @ +4096. Epilogue image (128x136) aliases bufs.
  __shared__ __align__(16) ushort_t S[24576];

  const int tid = threadIdx.x;
  const int wave = tid >> 6, lane = tid & 63;
  const int quad = lane >> 4, l15 = lane & 15;
  const int wm = wave >> 2, wn = wave & 3;
  const int lrow4 = lane >> 2, lcol8 = (lane & 3) << 3;

  // ---- XCD-pinned decode ----
  int bx = blockIdx.x;
  int task, xt, yt, b;
  if (bx < 432) {
    int slot = bx & 7, rest = bx >> 3;
    int y = rest % 6, vhi = rest / 6;
    int v = slot + 8 * vhi;
    task = 2; xt = v % 9; b = v / 9; yt = y;
  } else if (bx < 816) {
    int t = bx - 432;
    int slot = t & 7, rest = t >> 3;
    int x = rest % 6, qhi = rest / 6;
    int q = slot + 8 * qhi;
    task = 0; xt = x; yt = q & 7; b = q >> 3;
  } else {
    int t = bx - 816;
    int slot = t & 7, rest = t >> 3;
    int x = rest % 6, khi = rest / 6;
    int k = slot + 8 * khi;
    task = 1; xt = x; yt = k % 9; b = k / 9;
  }
  const int rowTile = yt * 128, colTile = xt * 128;
  const ushort_t* Xb = Xm + (size_t)b * LPAD * DMODEL;
  const ushort_t* A = task == 2 ? Wvb : Xb;
  const ushort_t* W = task == 2 ? Xb : (task == 0 ? Wqb : Wkb);
  const float* bias = task == 2 ? bv : (task == 0 ? bq : bk);

  const ushort_t* Arow = A + (size_t)(rowTile + wave * 16 + lrow4) * DMODEL + lcol8;
  const ushort_t* Wrow = W + (size_t)(colTile + wave * 16 + lrow4) * DMODEL + lcol8;

  f32x4 acc[4][2] = {};

  auto compute = [&](const ushort_t* cur) {
    bf16x8 af[4], bfr[2];
#pragma unroll
    for (int mt = 0; mt < 4; ++mt)
      af[mt] = *(const bf16x8*)&cur[(wm * 64 + mt * 16 + l15) * 32 + quad * 8];
#pragma unroll
    for (int nt = 0; nt < 2; ++nt)
      bfr[nt] = *(const bf16x8*)&cur[4096 + (wn * 32 + nt * 16 + l15) * 32 + quad * 8];
#pragma unroll
    for (int mt = 0; mt < 4; ++mt)
#pragma unroll
      for (int nt = 0; nt < 2; ++nt)
        acc[mt][nt] = __builtin_amdgcn_mfma_f32_16x16x32_bf16(af[mt], bfr[nt], acc[mt][nt], 0, 0, 0);
  };

  // prologue: tiles 0 and 1 in flight (4 loads/wave outstanding)
  stage16(Arow, S + wave * 512);
  stage16(Wrow, S + 4096 + wave * 512);
  stage16(Arow + 32, S + 8192 + wave * 512);
  stage16(Wrow + 32, S + 8192 + 4096 + wave * 512);

  for (int i = 0; i < 22; ++i) {
    WAITBAR_2;                      // tile i complete; tile i+1 still in flight
    ushort_t* nxt = S + ((i + 2) % 3) * 8192;
    int k0n = (i + 2) * 32;
    stage16(Arow + k0n, nxt + wave * 512);
    stage16(Wrow + k0n, nxt + 4096 + wave * 512);
    compute(S + (i % 3) * 8192);
  }
  WAITBAR_2; compute(S + 8192);     // i=22, 22%3=1
  WAITBAR_0; compute(S + 16384);    // i=23, 23%3=2

  // ---- epilogue: acc -> LDS bf16 image (stride 136) -> coalesced dwordx4 stores ----
  __syncthreads();                  // re-purpose S; all staging already drained
  const float scale = task == 0 ? CEXP : 1.0f;
#pragma unroll
  for (int mt = 0; mt < 4; ++mt)
#pragma unroll
    for (int nt = 0; nt < 2; ++nt) {
      int lr0 = wm * 64 + mt * 16 + quad * 4;
      int lc = wn * 32 + nt * 16 + l15;
#pragma unroll
      for (int r = 0; r < 4; ++r) {
        float bsv = (task == 2) ? bias[rowTile + lr0 + r] : bias[colTile + lc];
        S[(lr0 + r) * 136 + lc] = f2b((acc[mt][nt][r] + bsv) * scale);
      }
    }
  __syncthreads();

  {
    int row = tid >> 2;
    int segu = (tid & 3) * 32;
    bf16x8 v0 = *(const bf16x8*)&S[row * 136 + segu + 0];
    bf16x8 v1 = *(const bf16x8*)&S[row * 136 + segu + 8];
    bf16x8 v2 = *(const bf16x8*)&S[row * 136 + segu + 16];
    bf16x8 v3 = *(const bf16x8*)&S[row * 136 + segu + 24];
    if (task == 2) {
      int d = rowTile + row;
      ushort_t* gp = Vtb + (((size_t)b * NH + (d >> 6)) * DH + (d & 63)) * LPAD + colTile + segu;
      *(bf16x8*)(gp + 0) = v0;  *(bf16x8*)(gp + 8) = v1;
      *(bf16x8*)(gp + 16) = v2; *(bf16x8*)(gp + 24) = v3;
    } else {
      ushort_t* out = task == 0 ? Qb : Kb;
      const int Rows = task == 0 ? SEQ : LPAD;
      int colbase = colTile + segu;
      int h = colbase >> 6, dd = colbase & 63;
      ushort_t* gp = out + (((size_t)b * NH + h) * Rows + rowTile + row) * DH + dd;
      *(bf16x8*)(gp + 0) = v0;  *(bf16x8*)(gp + 8) = v1;
      *(bf16x8*)(gp + 16) = v2; *(bf16x8*)(gp + 24) = v3;
    }
  }
}

// Attention: triple-buffered 64-key tiles, raw-barrier vmcnt pipeline.
// Block = 128 q rows (4 waves x 32). Q pre-scaled so p = exp2(s). LDS = 64 KB -> 2 blocks/CU.
__global__ __launch_bounds__(256, 2) void attn(const ushort_t* __restrict__ Q,
                                               const ushort_t* __restrict__ K,
                                               const ushort_t* __restrict__ Vt,
                                               float* __restrict__ Out) {
  // 3 bufs @ i*8192: Ks @ +0 ([kk d-half][key64][32]), Vs @ +4096 ([kc key32][d64][32])
  __shared__ __align__(16) ushort_t KV[24576];
  __shared__ __align__(16) ushort_t Ps[8192];   // per wave 2048: [kc][row32][col32]

  const int tid = threadIdx.x, wave = tid >> 6, lane = tid & 63;
  const int quad = lane >> 4, l15 = lane & 15;
  const int lrow4 = lane >> 2, lcol8 = (lane & 3) << 3;
  const int bh = blockIdx.x, qt = blockIdx.y;
  const int h = bh % NH, b = bh / NH;

  const ushort_t* Qp = Q + (((size_t)b * NH + h) * SEQ + qt * 128) * DH;
  const ushort_t* Kp = K + ((size_t)b * NH + h) * LPAD * DH;
  const ushort_t* Vp = Vt + ((size_t)b * NH + h) * DH * LPAD;
  ushort_t* Pw = Ps + wave * 2048;

  bf16x8 qf[2][2];
#pragma unroll
  for (int mt = 0; mt < 2; ++mt)
#pragma unroll
    for (int kk = 0; kk < 2; ++kk)
      qf[mt][kk] = *(const bf16x8*)&Qp[(wave * 32 + mt * 16 + l15) * DH + kk * 32 + quad * 8];

  bf16x8 ones8;
#pragma unroll
  for (int j = 0; j < 8; ++j) ones8[j] = (short)0x3f80;

  f32x4 ob[2][4] = {};
  f32x4 obl[2] = {};

  // wave stages K chunks {wave, wave+4} and V chunks {wave, wave+4}: 4 loads/wave/tile
#define STAGE_KV(key0_, buf_)                                                        \
  {                                                                                  \
    _Pragma("unroll")                                                                \
    for (int s = 0; s < 2; ++s) {                                                    \
      int c = wave + s * 4;                                                          \
      int hi = c >> 2, lo = c & 3;                                                   \
      stage16(Kp + (size_t)((key0_) + lo * 16 + lrow4) * DH + hi * 32 + lcol8,       \
              (buf_) + c * 512);                                                     \
      stage16(Vp + (size_t)(lo * 16 + lrow4) * LPAD + (key0_) + hi * 32 + lcol8,     \
              (buf_) + 4096 + c * 512);                                              \
    }                                                                                \
  }

  auto computeAttn = [&](int kt, const ushort_t* cur) {
    // S = Q K^T : 32 q rows x 64 keys per wave
    f32x4 sc[2][4] = {};
#pragma unroll
    for (int kk = 0; kk < 2; ++kk)
#pragma unroll
      for (int nt = 0; nt < 4; ++nt) {
        bf16x8 kf = *(const bf16x8*)&cur[kk * 2048 + (nt * 16 + l15) * 32 + quad * 8];
#pragma unroll
        for (int mt = 0; mt < 2; ++mt)
          sc[mt][nt] = __builtin_amdgcn_mfma_f32_16x16x32_bf16(qf[mt][kk], kf, sc[mt][nt], 0, 0, 0);
      }

    // P = exp2(S) truncated to bf16, into chunked Ps [kc][row][col32]
    if (kt < 16) {
#pragma unroll
      for (int mt = 0; mt < 2; ++mt)
#pragma unroll
        for (int nt = 0; nt < 4; ++nt)
#pragma unroll
          for (int r = 0; r < 4; ++r) {
            union { float f; unsigned u; } cu;
            cu.f = EXP2F(sc[mt][nt][r]);
            Pw[(nt >> 1) * 1024 + (mt * 16 + quad * 4 + r) * 32 + (nt & 1) * 16 + l15] =
                (ushort_t)(cu.u >> 16);
          }
    } else {
      bool valid0 = (l15 < 8);  // keys 1024..1031 are nt==0, l15<8
#pragma unroll
      for (int mt = 0; mt < 2; ++mt)
#pragma unroll
        for (int nt = 0; nt < 4; ++nt) {
          bool valid = (nt == 0) && valid0;
#pragma unroll
          for (int r = 0; r < 4; ++r) {
            union { float f; unsigned u; } cu;
            cu.f = valid ? EXP2F(sc[mt][nt][r]) : 0.f;
            Pw[(nt >> 1) * 1024 + (mt * 16 + quad * 4 + r) * 32 + (nt & 1) * 16 + l15] =
                (ushort_t)(cu.u >> 16);
          }
        }
    }

    // O += P V ; l += P 1
#pragma unroll
    for (int kc = 0; kc < 2; ++kc) {
      bf16x8 pf[2];
#pragma unroll
      for (int mt = 0; mt < 2; ++mt)
        pf[mt] = *(const bf16x8*)&Pw[kc * 1024 + (mt * 16 + l15) * 32 + quad * 8];
#pragma unroll
      for (int dt = 0; dt < 4; ++dt) {
        bf16x8 vf = *(const bf16x8*)&cur[4096 + kc * 2048 + (dt * 16 + l15) * 32 + quad * 8];
#pragma unroll
        for (int mt = 0; mt < 2; ++mt)
          ob[mt][dt] = __builtin_amdgcn_mfma_f32_16x16x32_bf16(pf[mt], vf, ob[mt][dt], 0, 0, 0);
      }
#pragma unroll
      for (int mt = 0; mt < 2; ++mt)
        obl[mt] = __builtin_amdgcn_mfma_f32_16x16x32_bf16(pf[mt], ones8, obl[mt], 0, 0, 0);
    }
  };

  // prologue: tiles 0 and 1 in flight (8 loads/wave outstanding)
  STAGE_KV(0, KV)
  STAGE_KV(64, KV + 8192)

  for (int kt = 0; kt < 15; ++kt) {
    WAITBAR_4;                      // tile kt complete; tile kt+1 still in flight
    STAGE_KV((kt + 2) * 64, KV + ((kt + 2) % 3) * 8192)
    computeAttn(kt, KV + (kt % 3) * 8192);
  }
  WAITBAR_4; computeAttn(15, KV);            // 15%3 = 0
  WAITBAR_0; computeAttn(16, KV + 8192);     // 16%3 = 1

#pragma unroll
  for (int mt = 0; mt < 2; ++mt) {
    int row0 = qt * 128 + wave * 32 + mt * 16 + quad * 4;
    f32x4 linv;
#pragma unroll
    for (int r = 0; r < 4; ++r) linv[r] = 1.0f / obl[mt][r];
#pragma unroll
    for (int dt = 0; dt < 4; ++dt) {
      int col = h * DH + dt * 16 + l15;
#pragma unroll
      for (int r = 0; r < 4; ++r)
        Out[((size_t)b * SEQ + row0 + r) * DMODEL + col] = ob[mt][dt][r] * linv[r];
    }
  }
}

extern "C" void kernel_launch(void* const* d_in, const int* in_sizes, int n_in,
                              void* d_out, int out_size, void* d_ws, size_t ws_size,
                              hipStream_t stream) {
  const float* hidden = (const float*)d_in[0];
  const float* memv   = (const float*)d_in[1];
  const float* Wq = (const float*)d_in[2];
  const float* bq = (const float*)d_in[3];
  const float* Wk = (const float*)d_in[4];
  const float* bk = (const float*)d_in[5];
  const float* Wv = (const float*)d_in[6];
  const float* bv = (const float*)d_in[7];
  float* out = (float*)d_out;

  char* ws = (char*)d_ws;
  size_t off = 0;
  ushort_t* Xm  = (ushort_t*)(ws + off); off += (size_t)BATCH * LPAD * DMODEL * 2;
  ushort_t* Wqb = (ushort_t*)(ws + off); off += (size_t)DMODEL * DMODEL * 2;
  ushort_t* Wkb = (ushort_t*)(ws + off); off += (size_t)DMODEL * DMODEL * 2;
  ushort_t* Wvb = (ushort_t*)(ws + off); off += (size_t)DMODEL * DMODEL * 2;
  ushort_t* Qb  = (ushort_t*)(ws + off); off += (size_t)BATCH * NH * SEQ * DH * 2;
  ushort_t* Kb  = (ushort_t*)(ws + off); off += (size_t)BATCH * NH * LPAD * DH * 2;
  ushort_t* Vtb = (ushort_t*)(ws + off);

  prep<<<dim3(8640), 256, 0, stream>>>(hidden, memv, Wq, Wk, Wv, Xm, Wqb, Wkb, Wvb);
  gemm_fused<<<dim3(1248), 512, 0, stream>>>(Xm, Wqb, Wkb, Wvb, bq, bk, bv, Qb, Kb, Vtb);
  attn<<<dim3(96, 8), 256, 0, stream>>>(Qb, Kb, Vtb, out);
}